// Round 9
// baseline (616.605 us; speedup 1.0000x reference)
//
#include <hip/hip_runtime.h>
#include <hip/hip_fp16.h>

typedef _Float16 half8 __attribute__((ext_vector_type(8)));
typedef _Float16 half4 __attribute__((ext_vector_type(4)));
typedef float floatx4 __attribute__((ext_vector_type(4)));

constexpr int kS = 4096;
constexpr int kD = 1024;
constexpr int kH = 16;
constexpr int kDh = 64;
constexpr int kF = 4096;
constexpr int kNQKV = kF + 3 * kD;   // 7168
constexpr int kKOut = kF + kD;       // 5120

__device__ __forceinline__ void async_ld16(const void* g, void* l) {
  __builtin_amdgcn_global_load_lds(
      (const __attribute__((address_space(1))) void*)g,
      (__attribute__((address_space(3))) void*)l, 16, 0, 0);
}

// ---------------------------------------------------------------- all weight transposes in one launch
__global__ __launch_bounds__(256) void wtrans_all(
    const float* __restrict__ w_in, const float* __restrict__ wq,
    const float* __restrict__ wk, const float* __restrict__ wv,
    const float* __restrict__ w_mo, const float* __restrict__ w_ao,
    _Float16* __restrict__ Wqkv, _Float16* __restrict__ Wout) {
  __shared__ float t[32][33];
  int id = blockIdx.x;
  const float* src; _Float16* dst; int N, ldk, noff, koff, nt, kt;
  if (id < 4096)       { src = w_in; dst = Wqkv; N = kF; ldk = kD; noff = 0;        koff = 0;  nt = id & 127; kt = id >> 7; }
  else if (id < 5120)  { id -= 4096; src = wq;  dst = Wqkv; N = kD; ldk = kD; noff = kF;       koff = 0;  nt = id & 31; kt = id >> 5; }
  else if (id < 6144)  { id -= 5120; src = wk;  dst = Wqkv; N = kD; ldk = kD; noff = kF + kD;  koff = 0;  nt = id & 31; kt = id >> 5; }
  else if (id < 7168)  { id -= 6144; src = wv;  dst = Wqkv; N = kD; ldk = kD; noff = kF + 2*kD; koff = 0; nt = id & 31; kt = id >> 5; }
  else if (id < 11264) { id -= 7168; src = w_mo; dst = Wout; N = kD; ldk = kKOut; noff = 0;    koff = 0;  nt = id & 31; kt = id >> 5; }
  else                 { id -= 11264; src = w_ao; dst = Wout; N = kD; ldk = kKOut; noff = 0;   koff = kF; nt = id & 31; kt = id >> 5; }
  const int tid = threadIdx.x;
  const int n0 = nt * 32, k0 = kt * 32;
#pragma unroll
  for (int i = 0; i < 4; ++i) {
    const int kl = (tid >> 5) + i * 8, nl = tid & 31;
    t[kl][nl] = src[(size_t)(k0 + kl) * N + n0 + nl];
  }
  __syncthreads();
#pragma unroll
  for (int i = 0; i < 4; ++i) {
    const int nl = (tid >> 5) + i * 8, kl = tid & 31;
    dst[(size_t)(noff + n0 + nl) * ldk + koff + k0 + kl] = (_Float16)t[kl][nl];
  }
}

// fp16 transpose: src [R][C] -> dst [C][R]
__global__ __launch_bounds__(256) void htrans_kernel(
    const _Float16* __restrict__ src, _Float16* __restrict__ dst, int R, int C) {
  __shared__ _Float16 t[32][34];
  const int tid = threadIdx.x;
  const int c0 = blockIdx.x * 32, r0 = blockIdx.y * 32;
#pragma unroll
  for (int i = 0; i < 4; ++i) {
    const int rl = (tid >> 5) + i * 8, cl = tid & 31;
    t[rl][cl] = src[(size_t)(r0 + rl) * C + c0 + cl];
  }
  __syncthreads();
#pragma unroll
  for (int i = 0; i < 4; ++i) {
    const int cl = (tid >> 5) + i * 8, rl = tid & 31;
    dst[(size_t)(c0 + cl) * R + r0 + rl] = t[rl][cl];
  }
}

// ---------------------------------------------------------------- bias prep
__global__ __launch_bounds__(256) void biasprep_kernel(
    const float* b_in, const float* bq, const float* bk, const float* bv,
    const float* b_mo, const float* b_ao, float* bcat, float* bsum) {
  const int i = blockIdx.x * 256 + threadIdx.x;
  if (i < kF) bcat[i] = b_in[i];
  else if (i < kF + kD) bcat[i] = bq[i - kF];
  else if (i < kF + 2 * kD) bcat[i] = bk[i - kF - kD];
  else if (i < kNQKV) bcat[i] = bv[i - kF - 2 * kD];
  else if (i < kNQKV + kD) bsum[i - kNQKV] = b_mo[i - kNQKV] + b_ao[i - kNQKV];
}

// ---------------------------------------------------------------- LayerNorm (D=1024) -> fp16
__global__ __launch_bounds__(256) void ln_kernel(
    const float* __restrict__ x, const float* __restrict__ scale,
    const float* __restrict__ bias, _Float16* __restrict__ xn) {
  const int row = blockIdx.x;
  const int tid = threadIdx.x;
  const float* xr = x + (size_t)row * kD;
  float v[4];
  float s = 0.f, sq = 0.f;
#pragma unroll
  for (int i = 0; i < 4; ++i) {
    v[i] = xr[tid + 256 * i];
    s += v[i];
    sq += v[i] * v[i];
  }
  for (int off = 32; off; off >>= 1) {
    s += __shfl_xor(s, off);
    sq += __shfl_xor(sq, off);
  }
  __shared__ float red[8];
  const int wv = tid >> 6;
  if ((tid & 63) == 0) { red[wv] = s; red[wv + 4] = sq; }
  __syncthreads();
  s = red[0] + red[1] + red[2] + red[3];
  sq = red[4] + red[5] + red[6] + red[7];
  const float mean = s * (1.0f / kD);
  const float var = sq * (1.0f / kD) - mean * mean;
  const float rstd = rsqrtf(var + 1e-6f);
#pragma unroll
  for (int i = 0; i < 4; ++i) {
    int d = tid + 256 * i;
    xn[(size_t)row * kD + d] = (_Float16)((v[i] - mean) * rstd * scale[d] + bias[d]);
  }
}

// fast tanh-gelu
__device__ __forceinline__ float fast_gelu(float xv) {
  const float z = 0.7978845608028654f * (xv + 0.044715f * xv * xv * xv);
  const float u = exp2f(fminf(2.885390081777927f * z, 80.0f));
  return xv * u / (1.0f + u);
}

// ---------------------------------------------------------------- fused QKV+MLP-in GEMM (+fused qk-LayerNorm)
__global__ __launch_bounds__(256) void gemm_qkvin(
    const _Float16* __restrict__ A, const _Float16* __restrict__ Bp,
    const float* __restrict__ bcat, const float* __restrict__ qn_scale,
    const float* __restrict__ kn_scale, _Float16* __restrict__ ho,
    _Float16* __restrict__ q, _Float16* __restrict__ k, _Float16* __restrict__ v) {
  __shared__ alignas(16) _Float16 Ts[16 * 512];
  _Float16* As = Ts;
  _Float16* Bs = Ts + 8 * 512;

  const int tid = threadIdx.x;
  const int lane = tid & 63;
  const int wave = tid >> 6;
  const int wm = (wave >> 1) * 64;
  const int wn = (wave & 1) * 64;
  const int m0 = blockIdx.x * 128;
  const int n0 = blockIdx.y * 128;
  const int lrow = lane & 15;
  const int quad = lane >> 4;

  floatx4 acc[4][4] = {};

  for (int k0 = 0; k0 < kD; k0 += 32) {
    __syncthreads();
#pragma unroll
    for (int i = 0; i < 4; ++i) {
      const int chunk = wave * 4 + i;
      const int r = ((chunk & 7) << 4) + (lane >> 2);
      const int csrc = ((lane & 3) ^ ((r >> 1) & 3)) << 3;
      const _Float16* src = (chunk < 8)
          ? A + (size_t)(m0 + r) * kD + k0 + csrc
          : Bp + (size_t)(n0 + r) * kD + k0 + csrc;
      async_ld16(src, Ts + chunk * 512);
    }
    __syncthreads();

    half8 af[4], bf[4];
#pragma unroll
    for (int i = 0; i < 4; ++i) {
      const int ra = wm + i * 16 + lrow;
      const int rb = wn + i * 16 + lrow;
      af[i] = *reinterpret_cast<const half8*>(&As[ra * 32 + ((quad ^ ((ra >> 1) & 3)) << 3)]);
      bf[i] = *reinterpret_cast<const half8*>(&Bs[rb * 32 + ((quad ^ ((rb >> 1) & 3)) << 3)]);
    }
#pragma unroll
    for (int i = 0; i < 4; ++i)
#pragma unroll
      for (int j = 0; j < 4; ++j)
        acc[i][j] = __builtin_amdgcn_mfma_f32_16x16x32_f16(af[i], bf[j], acc[i][j], 0, 0, 0);
  }

  const int nblk = n0 + wn;
  if (nblk < kF) {
#pragma unroll
    for (int i = 0; i < 4; ++i) {
      const int gm = m0 + wm + i * 16 + quad * 4;
#pragma unroll
      for (int j = 0; j < 4; ++j) {
        const int gn = nblk + j * 16 + lrow;
        const float bn = bcat[gn];
#pragma unroll
        for (int r = 0; r < 4; ++r)
          ho[(size_t)(gm + r) * kKOut + gn] = (_Float16)fast_gelu(acc[i][j][r] + bn);
      }
    }
  } else if (nblk >= kF + 2 * kD) {
#pragma unroll
    for (int i = 0; i < 4; ++i) {
      const int gm = m0 + wm + i * 16 + quad * 4;
#pragma unroll
      for (int j = 0; j < 4; ++j) {
        const int gn = nblk + j * 16 + lrow;
        const float bn = bcat[gn];
#pragma unroll
        for (int r = 0; r < 4; ++r)
          v[(size_t)(gm + r) * kD + ((gn - kF) & (kD - 1))] = (_Float16)(acc[i][j][r] + bn);
      }
    }
  } else {
    const bool isq = nblk < kF + kD;
    const float* nsc = isq ? qn_scale : kn_scale;
    const float sm = isq ? 0.18033688f : 1.0f;  // q: fold 0.125*log2e
    _Float16* dst = isq ? q : k;
    const int col0 = (nblk - kF) & (kD - 1);
    float bj[4];
#pragma unroll
    for (int j = 0; j < 4; ++j) bj[j] = bcat[nblk + j * 16 + lrow];
#pragma unroll
    for (int i = 0; i < 4; ++i) {
      const int gm = m0 + wm + i * 16 + quad * 4;
#pragma unroll
      for (int r = 0; r < 4; ++r) {
        float vals[4], s1 = 0.f, s2 = 0.f;
#pragma unroll
        for (int j = 0; j < 4; ++j) {
          const float vv = acc[i][j][r] + bj[j];
          vals[j] = vv; s1 += vv; s2 += vv * vv;
        }
#pragma unroll
        for (int off = 1; off <= 8; off <<= 1) {
          s1 += __shfl_xor(s1, off);
          s2 += __shfl_xor(s2, off);
        }
        const float mean = s1 * (1.0f / 64.0f);
        const float rstd = rsqrtf(s2 * (1.0f / 64.0f) - mean * mean + 1e-6f);
#pragma unroll
        for (int j = 0; j < 4; ++j) {
          const int d = j * 16 + lrow;
          dst[(size_t)(gm + r) * kD + col0 + d] =
              (_Float16)((vals[j] - mean) * rstd * nsc[d] * sm);
        }
      }
    }
  }
}

// ---------------------------------------------------------------- prep: out = x + bsum ; zero Oacc/Lacc
__global__ __launch_bounds__(256) void prep_kernel(
    const float* __restrict__ x, const float* __restrict__ bsum,
    float* __restrict__ out, float* __restrict__ Oacc, float* __restrict__ Lacc) {
  const int i = blockIdx.x * 256 + threadIdx.x;
  if (i < kS * kD) {
    out[i] = x[i] + bsum[i & (kD - 1)];
    Oacc[i] = 0.f;
  } else if (i < kS * kD + kS * kH) {
    Lacc[i - kS * kD] = 0.f;
  }
}

// ---------------------------------------------------------------- fused out GEMM, 128x128, split-K=2, atomic accumulate
__global__ __launch_bounds__(256) void gemm_out(
    const _Float16* __restrict__ A, const _Float16* __restrict__ Bp,
    float* __restrict__ out) {
  __shared__ alignas(16) _Float16 Ts[16 * 512];
  _Float16* As = Ts;
  _Float16* Bs = Ts + 8 * 512;

  const int tid = threadIdx.x;
  const int lane = tid & 63;
  const int wave = tid >> 6;
  const int wm = (wave >> 1) * 64;
  const int wn = (wave & 1) * 64;
  const int m0 = blockIdx.x * 128;
  const int n0 = blockIdx.y * 128;
  const int kbeg = blockIdx.z * (kKOut / 2);
  const int lrow = lane & 15;
  const int quad = lane >> 4;

  floatx4 acc[4][4] = {};

  for (int k0 = kbeg; k0 < kbeg + kKOut / 2; k0 += 32) {
    __syncthreads();
#pragma unroll
    for (int i = 0; i < 4; ++i) {
      const int chunk = wave * 4 + i;
      const int r = ((chunk & 7) << 4) + (lane >> 2);
      const int csrc = ((lane & 3) ^ ((r >> 1) & 3)) << 3;
      const _Float16* src = (chunk < 8)
          ? A + (size_t)(m0 + r) * kKOut + k0 + csrc
          : Bp + (size_t)(n0 + r) * kKOut + k0 + csrc;
      async_ld16(src, Ts + chunk * 512);
    }
    __syncthreads();

    half8 af[4], bf[4];
#pragma unroll
    for (int i = 0; i < 4; ++i) {
      const int ra = wm + i * 16 + lrow;
      const int rb = wn + i * 16 + lrow;
      af[i] = *reinterpret_cast<const half8*>(&As[ra * 32 + ((quad ^ ((ra >> 1) & 3)) << 3)]);
      bf[i] = *reinterpret_cast<const half8*>(&Bs[rb * 32 + ((quad ^ ((rb >> 1) & 3)) << 3)]);
    }
#pragma unroll
    for (int i = 0; i < 4; ++i)
#pragma unroll
      for (int j = 0; j < 4; ++j)
        acc[i][j] = __builtin_amdgcn_mfma_f32_16x16x32_f16(af[i], bf[j], acc[i][j], 0, 0, 0);
  }

#pragma unroll
  for (int i = 0; i < 4; ++i) {
    const int gm = m0 + wm + i * 16 + quad * 4;
#pragma unroll
    for (int j = 0; j < 4; ++j) {
      const int gn = n0 + wn + j * 16 + lrow;
#pragma unroll
      for (int r = 0; r < 4; ++r)
        atomicAdd(out + (size_t)(gm + r) * kD + gn, acc[i][j][r]);
    }
  }
}

// ---------------------------------------------------------------- flash attention v6: register-resident P
// S^T = K·Q^T via 16x16x32 (A=K, B=Q): C-layout key=quad*4+r, q=lrow == A-layout
// of 16x16x16 PV MFMA (m=q=lane&15, k=key=quad*4+j) -> P never touches LDS.
// grid 1536: xcd=id&7 (2 heads/XCD, K/V in L2), 32 pairs {p,63-p}, 3 k-splits.
// No-max softmax (|s|<=8 after qk-LN; 0.125*log2e folded into q).
__global__ __launch_bounds__(256) void fattn_kernel(
    const _Float16* __restrict__ Q, const _Float16* __restrict__ K,
    const _Float16* __restrict__ Vt, float* __restrict__ Oacc,
    float* __restrict__ Lacc) {
  __shared__ alignas(16) _Float16 Qs[64 * 64];   // 8 KB swizzled (chunk ^ (r&7))
  __shared__ alignas(16) _Float16 Ks[64 * 64];   // 8 KB rows=key
  __shared__ alignas(16) _Float16 Vs[64 * 64];   // 8 KB rows=dh

  const int tid = threadIdx.x;
  const int lane = tid & 63;
  const int wave = tid >> 6;
  const int lrow = lane & 15;
  const int quad = lane >> 4;

  const int id = blockIdx.x;
  const int xcd = id & 7;
  const int idx = id >> 3;            // 0..191 per XCD
  const int h = (xcd << 1) | (idx & 1);
  const int rem = idx >> 1;           // 0..95
  const int pair = rem & 31;          // 32 pairs of 64-row q-tiles
  const int split = rem >> 5;         // 0..2

  const int rs = lane >> 3;
  const int cs = lane & 7;
  constexpr float kOff = 11.5415603f;  // 8*log2(e)

  for (int pass = 0; pass < 2; ++pass) {
    const int qtile = pass ? (63 - pair) : pair;
    const int qbase = qtile * 64;

    __syncthreads();
#pragma unroll
    for (int i = 0; i < 2; ++i) {  // Q: 8 chunks x 8 rows
      const int chunk = wave * 2 + i;
      const int r = chunk * 8 + rs;
      async_ld16(Q + (size_t)(qbase + r) * kD + h * kDh + ((cs ^ (r & 7)) << 3),
                 Qs + chunk * 512);
    }
    __syncthreads();

    half8 qf[2];  // B-operand (n=q=lane&15, k=quad*8+j)
#pragma unroll
    for (int kt = 0; kt < 2; ++kt) {
      const int row = wave * 16 + lrow;
      qf[kt] = *reinterpret_cast<const half8*>(
          &Qs[row * 64 + (((kt * 4 + quad) ^ (row & 7)) << 3)]);
    }

    float lst = 0.f;       // per-lane: q=lrow, keys of this quad
    floatx4 oacc[4] = {};  // [jd]: O[q=quad*4+rr][d=jd*16+lrow]
    const int qw = qbase + wave * 16;

    for (int t = split; t <= qtile; t += 3) {
      const int k0 = t * 64;
      __syncthreads();
#pragma unroll
      for (int i = 0; i < 4; ++i) {
        const int c2 = wave * 4 + i;
        if (c2 < 8) {
          const int r = c2 * 8 + rs;
          async_ld16(K + (size_t)(k0 + r) * kD + h * kDh + ((cs ^ (r & 7)) << 3),
                     Ks + c2 * 512);
        } else {
          const int c = c2 - 8;
          const int r = c * 8 + rs;
          async_ld16(Vt + (size_t)(h * kDh + r) * kS + k0 + ((cs ^ (r & 7)) << 3),
                     Vs + c * 512);
        }
      }
      __syncthreads();

      const bool diag = (t == qtile);

      // S^T: sacc[jt] rows=key k0+jt*16+quad*4+r, cols=q qw+lrow
      floatx4 sacc[4] = {};
#pragma unroll
      for (int jt = 0; jt < 4; ++jt) {
        if (diag && jt > wave) continue;  // all keys > all q
#pragma unroll
        for (int kt = 0; kt < 2; ++kt) {
          const int ar = jt * 16 + lrow;  // key row
          half8 kf = *reinterpret_cast<const half8*>(
              &Ks[ar * 64 + (((kt * 4 + quad) ^ (ar & 7)) << 3)]);
          sacc[jt] = __builtin_amdgcn_mfma_f32_16x16x32_f16(kf, qf[kt], sacc[jt], 0, 0, 0);
        }
      }

      if (diag) {  // causal: key > q -> -inf (covers skipped jt blocks too: sacc=0)
        const int qg = qw + lrow;
#pragma unroll
        for (int jt = 0; jt < 4; ++jt) {
          const int kg = k0 + jt * 16 + quad * 4;
#pragma unroll
          for (int r = 0; r < 4; ++r)
            if (kg + r > qg) sacc[jt][r] = -1e30f;
        }
      }

      // p = exp2(s - 8log2e) <= 1; pack to fp16 A-operands, accumulate l
      half4 pf[4];
#pragma unroll
      for (int jt = 0; jt < 4; ++jt) {
        float p0 = exp2f(sacc[jt][0] - kOff);
        float p1 = exp2f(sacc[jt][1] - kOff);
        float p2 = exp2f(sacc[jt][2] - kOff);
        float p3 = exp2f(sacc[jt][3] - kOff);
        lst += (p0 + p1) + (p2 + p3);
        pf[jt][0] = (_Float16)p0; pf[jt][1] = (_Float16)p1;
        pf[jt][2] = (_Float16)p2; pf[jt][3] = (_Float16)p3;
      }

      // O += P V via 16x16x16: A=pf[kt(key block)], B=Vs[d=jd*16+lrow][key]
      const int ktmax = diag ? (wave + 1) : 4;
      for (int kt = 0; kt < ktmax; ++kt) {
        const int coff = ((((kt << 1) + (quad >> 1)) ^ (lrow & 7)) << 3) + ((quad & 1) << 2);
#pragma unroll
        for (int jd = 0; jd < 4; ++jd) {
          half4 vf = *reinterpret_cast<const half4*>(
              &Vs[(jd * 16 + lrow) * 64 + coff]);
          oacc[jd] = __builtin_amdgcn_mfma_f32_16x16x16f16(pf[kt], vf, oacc[jd], 0, 0, 0);
        }
      }
    }

    // epilogue: l[q=lrow] = sum over quads; O atomic-accumulate
    lst += __shfl_xor(lst, 16);
    lst += __shfl_xor(lst, 32);
    if (lane < 16) atomicAdd(Lacc + (qw + lane) * kH + h, lst);
#pragma unroll
    for (int jd = 0; jd < 4; ++jd)
#pragma unroll
      for (int rr = 0; rr < 4; ++rr)
        atomicAdd(Oacc + ((size_t)(qw + quad * 4 + rr) * kH + h) * kDh + jd * 16 + lrow,
                  oacc[jd][rr]);
  }
}

// ---------------------------------------------------------------- normalize: ho attn columns = Oacc / Lacc
__global__ __launch_bounds__(256) void norm_kernel(
    const float* __restrict__ Oacc, const float* __restrict__ Lacc,
    _Float16* __restrict__ ho) {
  const int idx = blockIdx.x * 256 + threadIdx.x;
  const int q = idx >> 10, rem = idx & 1023;
  const float l = Lacc[(q << 4) + (rem >> 6)];
  ho[(size_t)q * kKOut + kF + rem] = (_Float16)(Oacc[idx] / l);
}

// ---------------------------------------------------------------- launch
extern "C" void kernel_launch(void* const* d_in, const int* in_sizes, int n_in,
                              void* d_out, int out_size, void* d_ws, size_t ws_size,
                              hipStream_t stream) {
  const float* x        = (const float*)d_in[0];
  const float* ln_scale = (const float*)d_in[2];
  const float* ln_bias  = (const float*)d_in[3];
  const float* w_in     = (const float*)d_in[4];
  const float* b_in     = (const float*)d_in[5];
  const float* wq       = (const float*)d_in[6];
  const float* bq       = (const float*)d_in[7];
  const float* wk       = (const float*)d_in[8];
  const float* bk       = (const float*)d_in[9];
  const float* wv       = (const float*)d_in[10];
  const float* bv       = (const float*)d_in[11];
  const float* qn_scale = (const float*)d_in[12];
  const float* kn_scale = (const float*)d_in[13];
  const float* w_mo     = (const float*)d_in[14];
  const float* b_mo     = (const float*)d_in[15];
  const float* w_ao     = (const float*)d_in[16];
  const float* b_ao     = (const float*)d_in[17];
  float* out = (float*)d_out;

  char* ws = (char*)d_ws;
  size_t off = 0;
  auto alloc = [&](size_t bytes) { char* p = ws + off; off += bytes; return p; };
  // alias zone: xn+Wqkv dead after gemm_qkvin; Oacc/Lacc overlay
  char* zone = (char*)alloc((size_t)kS * kD * 2 + (size_t)kNQKV * kD * 2);
  _Float16* xn   = (_Float16*)zone;
  _Float16* Wqkv = (_Float16*)(zone + (size_t)kS * kD * 2);
  float* Oacc = (float*)zone;
  float* Lacc = (float*)(zone + (size_t)kS * kD * 4);
  _Float16* Wout = (_Float16*)alloc((size_t)kD * kKOut * 2);
  float*    bcat = (float*)alloc((size_t)kNQKV * 4);
  float*    bsum = (float*)alloc((size_t)kD * 4);
  _Float16* ho   = (_Float16*)alloc((size_t)kS * kKOut * 2);
  _Float16* q_h  = (_Float16*)alloc((size_t)kS * kD * 2);
  _Float16* k_h  = (_Float16*)alloc((size_t)kS * kD * 2);
  _Float16* v_h  = (_Float16*)alloc((size_t)kS * kD * 2);
  _Float16* v_t  = (_Float16*)alloc((size_t)kS * kD * 2);

  wtrans_all<<<12288, 256, 0, stream>>>(w_in, wq, wk, wv, w_mo, w_ao, Wqkv, Wout);
  biasprep_kernel<<<(kNQKV + kD + 255) / 256, 256, 0, stream>>>(
      b_in, bq, bk, bv, b_mo, b_ao, bcat, bsum);
  ln_kernel<<<kS, 256, 0, stream>>>(x, ln_scale, ln_bias, xn);

  gemm_qkvin<<<dim3(kS / 128, kNQKV / 128), 256, 0, stream>>>(
      xn, Wqkv, bcat, qn_scale, kn_scale, ho, q_h, k_h, v_h);

  htrans_kernel<<<dim3(kD / 32, kS / 32), 256, 0, stream>>>(v_h, v_t, kS, kD);

  prep_kernel<<<(kS * kD + kS * kH + 255) / 256, 256, 0, stream>>>(
      x, bsum, out, Oacc, Lacc);

  fattn_kernel<<<1536, 256, 0, stream>>>(q_h, k_h, v_t, Oacc, Lacc);

  norm_kernel<<<kS * kD / 256, 256, 0, stream>>>(Oacc, Lacc, ho);

  gemm_out<<<dim3(kS / 128, kD / 128, 2), 256, 0, stream>>>(ho, Wout, out);
}

// Round 10
// 471.256 us; speedup vs baseline: 1.3084x; 1.3084x over previous
//
#include <hip/hip_runtime.h>
#include <hip/hip_fp16.h>

typedef _Float16 half8 __attribute__((ext_vector_type(8)));
typedef float floatx4 __attribute__((ext_vector_type(4)));

constexpr int kS = 4096;
constexpr int kD = 1024;
constexpr int kH = 16;
constexpr int kDh = 64;
constexpr int kF = 4096;
constexpr int kNQKV = kF + 3 * kD;   // 7168
constexpr int kKOut = kF + kD;       // 5120

__device__ __forceinline__ void async_ld16(const void* g, void* l) {
  __builtin_amdgcn_global_load_lds(
      (const __attribute__((address_space(1))) void*)g,
      (__attribute__((address_space(3))) void*)l, 16, 0, 0);
}

// ---------------------------------------------------------------- prep0: weight transposes (12288 blocks) + LayerNorm (4096 blocks)
__global__ __launch_bounds__(256) void prep0_kernel(
    const float* __restrict__ w_in, const float* __restrict__ wq,
    const float* __restrict__ wk, const float* __restrict__ wv,
    const float* __restrict__ w_mo, const float* __restrict__ w_ao,
    _Float16* __restrict__ Wqkv, _Float16* __restrict__ Wout,
    const float* __restrict__ x, const float* __restrict__ ln_scale,
    const float* __restrict__ ln_bias, _Float16* __restrict__ xn) {
  __shared__ float t[32][33];
  __shared__ float red[8];
  int id = blockIdx.x;
  const int tid = threadIdx.x;

  if (id >= 12288) {  // ---- LayerNorm row
    const int row = id - 12288;
    const float* xr = x + (size_t)row * kD;
    float v[4];
    float s = 0.f, sq = 0.f;
#pragma unroll
    for (int i = 0; i < 4; ++i) {
      v[i] = xr[tid + 256 * i];
      s += v[i];
      sq += v[i] * v[i];
    }
    for (int off = 32; off; off >>= 1) {
      s += __shfl_xor(s, off);
      sq += __shfl_xor(sq, off);
    }
    const int wv2 = tid >> 6;
    if ((tid & 63) == 0) { red[wv2] = s; red[wv2 + 4] = sq; }
    __syncthreads();
    s = red[0] + red[1] + red[2] + red[3];
    sq = red[4] + red[5] + red[6] + red[7];
    const float mean = s * (1.0f / kD);
    const float var = sq * (1.0f / kD) - mean * mean;
    const float rstd = rsqrtf(var + 1e-6f);
#pragma unroll
    for (int i = 0; i < 4; ++i) {
      int d = tid + 256 * i;
      xn[(size_t)row * kD + d] = (_Float16)((v[i] - mean) * rstd * ln_scale[d] + ln_bias[d]);
    }
    return;
  }

  // ---- weight transpose tile
  const float* src; _Float16* dst; int N, ldk, noff, koff, nt, kt;
  if (id < 4096)       { src = w_in; dst = Wqkv; N = kF; ldk = kD; noff = 0;        koff = 0;  nt = id & 127; kt = id >> 7; }
  else if (id < 5120)  { id -= 4096; src = wq;  dst = Wqkv; N = kD; ldk = kD; noff = kF;       koff = 0;  nt = id & 31; kt = id >> 5; }
  else if (id < 6144)  { id -= 5120; src = wk;  dst = Wqkv; N = kD; ldk = kD; noff = kF + kD;  koff = 0;  nt = id & 31; kt = id >> 5; }
  else if (id < 7168)  { id -= 6144; src = wv;  dst = Wqkv; N = kD; ldk = kD; noff = kF + 2*kD; koff = 0; nt = id & 31; kt = id >> 5; }
  else if (id < 11264) { id -= 7168; src = w_mo; dst = Wout; N = kD; ldk = kKOut; noff = 0;    koff = 0;  nt = id & 31; kt = id >> 5; }
  else                 { id -= 11264; src = w_ao; dst = Wout; N = kD; ldk = kKOut; noff = 0;   koff = kF; nt = id & 31; kt = id >> 5; }
  const int n0 = nt * 32, k0 = kt * 32;
#pragma unroll
  for (int i = 0; i < 4; ++i) {
    const int kl = (tid >> 5) + i * 8, nl = tid & 31;
    t[kl][nl] = src[(size_t)(k0 + kl) * N + n0 + nl];
  }
  __syncthreads();
#pragma unroll
  for (int i = 0; i < 4; ++i) {
    const int nl = (tid >> 5) + i * 8, kl = tid & 31;
    dst[(size_t)(noff + n0 + nl) * ldk + koff + k0 + kl] = (_Float16)t[kl][nl];
  }
}

// fp16 transpose: src [R][C] -> dst [C][R]
__global__ __launch_bounds__(256) void htrans_kernel(
    const _Float16* __restrict__ src, _Float16* __restrict__ dst, int R, int C) {
  __shared__ _Float16 t[32][34];
  const int tid = threadIdx.x;
  const int c0 = blockIdx.x * 32, r0 = blockIdx.y * 32;
#pragma unroll
  for (int i = 0; i < 4; ++i) {
    const int rl = (tid >> 5) + i * 8, cl = tid & 31;
    t[rl][cl] = src[(size_t)(r0 + rl) * C + c0 + cl];
  }
  __syncthreads();
#pragma unroll
  for (int i = 0; i < 4; ++i) {
    const int cl = (tid >> 5) + i * 8, rl = tid & 31;
    dst[(size_t)(c0 + cl) * R + r0 + rl] = t[rl][cl];
  }
}

// fast tanh-gelu
__device__ __forceinline__ float fast_gelu(float xv) {
  const float z = 0.7978845608028654f * (xv + 0.044715f * xv * xv * xv);
  const float u = exp2f(fminf(2.885390081777927f * z, 80.0f));
  return xv * u / (1.0f + u);
}

// ---------------------------------------------------------------- fused QKV+MLP-in GEMM (+fused qk-LayerNorm)
__global__ __launch_bounds__(256) void gemm_qkvin(
    const _Float16* __restrict__ A, const _Float16* __restrict__ Bp,
    const float* __restrict__ b_in, const float* __restrict__ bq,
    const float* __restrict__ bk, const float* __restrict__ bv,
    const float* __restrict__ qn_scale, const float* __restrict__ kn_scale,
    _Float16* __restrict__ ho, _Float16* __restrict__ q,
    _Float16* __restrict__ k, _Float16* __restrict__ v) {
  __shared__ alignas(16) _Float16 Ts[16 * 512];
  _Float16* As = Ts;
  _Float16* Bs = Ts + 8 * 512;

  const int tid = threadIdx.x;
  const int lane = tid & 63;
  const int wave = tid >> 6;
  const int wm = (wave >> 1) * 64;
  const int wn = (wave & 1) * 64;
  const int m0 = blockIdx.x * 128;
  const int n0 = blockIdx.y * 128;
  const int lrow = lane & 15;
  const int quad = lane >> 4;

  floatx4 acc[4][4] = {};

  for (int k0 = 0; k0 < kD; k0 += 32) {
    __syncthreads();
#pragma unroll
    for (int i = 0; i < 4; ++i) {
      const int chunk = wave * 4 + i;
      const int r = ((chunk & 7) << 4) + (lane >> 2);
      const int csrc = ((lane & 3) ^ ((r >> 1) & 3)) << 3;
      const _Float16* src = (chunk < 8)
          ? A + (size_t)(m0 + r) * kD + k0 + csrc
          : Bp + (size_t)(n0 + r) * kD + k0 + csrc;
      async_ld16(src, Ts + chunk * 512);
    }
    __syncthreads();

    half8 af[4], bf[4];
#pragma unroll
    for (int i = 0; i < 4; ++i) {
      const int ra = wm + i * 16 + lrow;
      const int rb = wn + i * 16 + lrow;
      af[i] = *reinterpret_cast<const half8*>(&As[ra * 32 + ((quad ^ ((ra >> 1) & 3)) << 3)]);
      bf[i] = *reinterpret_cast<const half8*>(&Bs[rb * 32 + ((quad ^ ((rb >> 1) & 3)) << 3)]);
    }
#pragma unroll
    for (int i = 0; i < 4; ++i)
#pragma unroll
      for (int j = 0; j < 4; ++j)
        acc[i][j] = __builtin_amdgcn_mfma_f32_16x16x32_f16(af[i], bf[j], acc[i][j], 0, 0, 0);
  }

  const int nblk = n0 + wn;
  if (nblk < kF) {  // gelu -> ho
#pragma unroll
    for (int i = 0; i < 4; ++i) {
      const int gm = m0 + wm + i * 16 + quad * 4;
#pragma unroll
      for (int j = 0; j < 4; ++j) {
        const int gn = nblk + j * 16 + lrow;
        const float bn = b_in[gn];
#pragma unroll
        for (int r = 0; r < 4; ++r)
          ho[(size_t)(gm + r) * kKOut + gn] = (_Float16)fast_gelu(acc[i][j][r] + bn);
      }
    }
  } else if (nblk >= kF + 2 * kD) {  // v plain
#pragma unroll
    for (int i = 0; i < 4; ++i) {
      const int gm = m0 + wm + i * 16 + quad * 4;
#pragma unroll
      for (int j = 0; j < 4; ++j) {
        const int gn = nblk + j * 16 + lrow;
        const float bn = bv[(gn - kF) & (kD - 1)];
#pragma unroll
        for (int r = 0; r < 4; ++r)
          v[(size_t)(gm + r) * kD + ((gn - kF) & (kD - 1))] = (_Float16)(acc[i][j][r] + bn);
      }
    }
  } else {  // q or k: fused per-head LayerNorm (wave's 64 cols = one head)
    const bool isq = nblk < kF + kD;
    const float* nsc = isq ? qn_scale : kn_scale;
    const float* nb = isq ? bq : bk;
    const float sm = isq ? 0.18033688f : 1.0f;  // q: fold 0.125*log2e
    _Float16* dst = isq ? q : k;
    const int col0 = (nblk - kF) & (kD - 1);
    float bj[4];
#pragma unroll
    for (int j = 0; j < 4; ++j) bj[j] = nb[col0 + j * 16 + lrow];
#pragma unroll
    for (int i = 0; i < 4; ++i) {
      const int gm = m0 + wm + i * 16 + quad * 4;
#pragma unroll
      for (int r = 0; r < 4; ++r) {
        float vals[4], s1 = 0.f, s2 = 0.f;
#pragma unroll
        for (int j = 0; j < 4; ++j) {
          const float vv = acc[i][j][r] + bj[j];
          vals[j] = vv; s1 += vv; s2 += vv * vv;
        }
#pragma unroll
        for (int off = 1; off <= 8; off <<= 1) {
          s1 += __shfl_xor(s1, off);
          s2 += __shfl_xor(s2, off);
        }
        const float mean = s1 * (1.0f / 64.0f);
        const float rstd = rsqrtf(s2 * (1.0f / 64.0f) - mean * mean + 1e-6f);
#pragma unroll
        for (int j = 0; j < 4; ++j) {
          const int d = j * 16 + lrow;
          dst[(size_t)(gm + r) * kD + col0 + d] =
              (_Float16)((vals[j] - mean) * rstd * nsc[d] * sm);
        }
      }
    }
  }
}

// ---------------------------------------------------------------- prep: out = x + b_mo + b_ao ; zero Oacc/Lacc
__global__ __launch_bounds__(256) void prep_kernel(
    const float* __restrict__ x, const float* __restrict__ b_mo,
    const float* __restrict__ b_ao, float* __restrict__ out,
    float* __restrict__ Oacc, float* __restrict__ Lacc) {
  const int i = blockIdx.x * 256 + threadIdx.x;
  if (i < kS * kD) {
    const int d = i & (kD - 1);
    out[i] = x[i] + b_mo[d] + b_ao[d];
    Oacc[i] = 0.f;
  } else if (i < kS * kD + kS * kH) {
    Lacc[i - kS * kD] = 0.f;
  }
}

// ---------------------------------------------------------------- fused out GEMM, 128x128, split-K=2, atomic accumulate
__global__ __launch_bounds__(256) void gemm_out(
    const _Float16* __restrict__ A, const _Float16* __restrict__ Bp,
    float* __restrict__ out) {
  __shared__ alignas(16) _Float16 Ts[16 * 512];
  _Float16* As = Ts;
  _Float16* Bs = Ts + 8 * 512;

  const int tid = threadIdx.x;
  const int lane = tid & 63;
  const int wave = tid >> 6;
  const int wm = (wave >> 1) * 64;
  const int wn = (wave & 1) * 64;
  const int m0 = blockIdx.x * 128;
  const int n0 = blockIdx.y * 128;
  const int kbeg = blockIdx.z * (kKOut / 2);
  const int lrow = lane & 15;
  const int quad = lane >> 4;

  floatx4 acc[4][4] = {};

  for (int k0 = kbeg; k0 < kbeg + kKOut / 2; k0 += 32) {
    __syncthreads();
#pragma unroll
    for (int i = 0; i < 4; ++i) {
      const int chunk = wave * 4 + i;
      const int r = ((chunk & 7) << 4) + (lane >> 2);
      const int csrc = ((lane & 3) ^ ((r >> 1) & 3)) << 3;
      const _Float16* src = (chunk < 8)
          ? A + (size_t)(m0 + r) * kKOut + k0 + csrc
          : Bp + (size_t)(n0 + r) * kKOut + k0 + csrc;
      async_ld16(src, Ts + chunk * 512);
    }
    __syncthreads();

    half8 af[4], bf[4];
#pragma unroll
    for (int i = 0; i < 4; ++i) {
      const int ra = wm + i * 16 + lrow;
      const int rb = wn + i * 16 + lrow;
      af[i] = *reinterpret_cast<const half8*>(&As[ra * 32 + ((quad ^ ((ra >> 1) & 3)) << 3)]);
      bf[i] = *reinterpret_cast<const half8*>(&Bs[rb * 32 + ((quad ^ ((rb >> 1) & 3)) << 3)]);
    }
#pragma unroll
    for (int i = 0; i < 4; ++i)
#pragma unroll
      for (int j = 0; j < 4; ++j)
        acc[i][j] = __builtin_amdgcn_mfma_f32_16x16x32_f16(af[i], bf[j], acc[i][j], 0, 0, 0);
  }

#pragma unroll
  for (int i = 0; i < 4; ++i) {
    const int gm = m0 + wm + i * 16 + quad * 4;
#pragma unroll
    for (int j = 0; j < 4; ++j) {
      const int gn = n0 + wn + j * 16 + lrow;
#pragma unroll
      for (int r = 0; r < 4; ++r)
        atomicAdd(out + (size_t)(gm + r) * kD + gn, acc[i][j][r]);
    }
  }
}

// ---------------------------------------------------------------- flash attention (R5 config: measured-best 102 us)
// grid (32, 16, 2): pair of 64-row q-tiles {p,63-p} x head x 2 k-splits.
// P through LDS (stride 72), 16x16x32 PV. No-max softmax (|s|<=8 after
// qk-LN; 0.125*log2e folded into q), per-lane l, additive combine via atomics.
__global__ __launch_bounds__(256) void fattn_kernel(
    const _Float16* __restrict__ Q, const _Float16* __restrict__ K,
    const _Float16* __restrict__ Vt, float* __restrict__ Oacc,
    float* __restrict__ Lacc) {
  __shared__ alignas(16) _Float16 Qs[64 * 64];   // 8 KB swizzled (chunk ^ (r&7))
  __shared__ alignas(16) _Float16 Ks[64 * 64];   // 8 KB rows=key
  __shared__ alignas(16) _Float16 Vs[64 * 64];   // 8 KB rows=dh
  __shared__ alignas(16) _Float16 Ps[64 * 72];   // 9 KB padded

  const int tid = threadIdx.x;
  const int lane = tid & 63;
  const int wave = tid >> 6;
  const int lrow = lane & 15;
  const int quad = lane >> 4;
  const int h = blockIdx.y;
  const int pair = blockIdx.x;
  const int split = blockIdx.z;

  const int rs = lane >> 3;
  const int cs = lane & 7;
  constexpr float kOff = 11.5415603f;  // 8*log2(e)

  for (int pass = 0; pass < 2; ++pass) {
    const int qtile = pass ? (63 - pair) : pair;
    const int qbase = qtile * 64;

    __syncthreads();
#pragma unroll
    for (int i = 0; i < 2; ++i) {  // Q: 8 chunks x 8 rows
      const int chunk = wave * 2 + i;
      const int r = chunk * 8 + rs;
      async_ld16(Q + (size_t)(qbase + r) * kD + h * kDh + ((cs ^ (r & 7)) << 3),
                 Qs + chunk * 512);
    }
    __syncthreads();

    half8 qf[2];
#pragma unroll
    for (int kt = 0; kt < 2; ++kt) {
      const int row = wave * 16 + lrow;
      qf[kt] = *reinterpret_cast<const half8*>(
          &Qs[row * 64 + (((kt * 4 + quad) ^ (row & 7)) << 3)]);
    }

    float lst[4] = {0.f, 0.f, 0.f, 0.f};
    floatx4 oacc[4] = {};
    const int qw = qbase + wave * 16;

    for (int t = split; t <= qtile; t += 2) {
      const int k0 = t * 64;
      __syncthreads();
#pragma unroll
      for (int i = 0; i < 4; ++i) {
        const int c2 = wave * 4 + i;
        if (c2 < 8) {
          const int r = c2 * 8 + rs;
          async_ld16(K + (size_t)(k0 + r) * kD + h * kDh + ((cs ^ (r & 7)) << 3),
                     Ks + c2 * 512);
        } else {
          const int c = c2 - 8;
          const int r = c * 8 + rs;
          async_ld16(Vt + (size_t)(h * kDh + r) * kS + k0 + ((cs ^ (r & 7)) << 3),
                     Vs + c * 512);
        }
      }
      __syncthreads();

      const bool diag = (t == qtile);

      floatx4 sacc[4] = {};
#pragma unroll
      for (int jt = 0; jt < 4; ++jt) {
        if (diag && jt > wave) continue;  // fully-masked key block
#pragma unroll
        for (int kt = 0; kt < 2; ++kt) {
          const int rb = jt * 16 + lrow;
          half8 bfk = *reinterpret_cast<const half8*>(
              &Ks[rb * 64 + (((kt * 4 + quad) ^ (rb & 7)) << 3)]);
          sacc[jt] = __builtin_amdgcn_mfma_f32_16x16x32_f16(qf[kt], bfk, sacc[jt], 0, 0, 0);
        }
      }

      if (diag) {
#pragma unroll
        for (int jt = 0; jt < 4; ++jt) {
          const int kg = k0 + jt * 16 + lrow;
#pragma unroll
          for (int r = 0; r < 4; ++r)
            if (kg > qw + quad * 4 + r) sacc[jt][r] = -1e30f;
        }
      }

#pragma unroll
      for (int jt = 0; jt < 4; ++jt)
#pragma unroll
        for (int r = 0; r < 4; ++r) {
          const float p = exp2f(sacc[jt][r] - kOff);
          sacc[jt][r] = p;
          lst[r] += p;
        }

#pragma unroll
      for (int jt = 0; jt < 4; ++jt)
#pragma unroll
        for (int r = 0; r < 4; ++r)
          Ps[(wave * 16 + quad * 4 + r) * 72 + jt * 16 + lrow] = (_Float16)sacc[jt][r];

      const int ktmax = (diag && wave < 2) ? 1 : 2;
      for (int kt = 0; kt < ktmax; ++kt) {
        half8 pf = *reinterpret_cast<const half8*>(
            &Ps[(wave * 16 + lrow) * 72 + (kt * 4 + quad) * 8]);
#pragma unroll
        for (int jt = 0; jt < 4; ++jt) {
          const int rb = jt * 16 + lrow;
          half8 vf = *reinterpret_cast<const half8*>(
              &Vs[rb * 64 + (((kt * 4 + quad) ^ (rb & 7)) << 3)]);
          oacc[jt] = __builtin_amdgcn_mfma_f32_16x16x32_f16(pf, vf, oacc[jt], 0, 0, 0);
        }
      }
    }

    // epilogue: reduce l over 16 cols, accumulate partials
#pragma unroll
    for (int r = 0; r < 4; ++r)
#pragma unroll
      for (int off = 8; off; off >>= 1) lst[r] += __shfl_xor(lst[r], off);
#pragma unroll
    for (int r = 0; r < 4; ++r) {
      const int qg = qw + quad * 4 + r;
      if (lrow == 0) atomicAdd(Lacc + qg * kH + h, lst[r]);
#pragma unroll
      for (int jt = 0; jt < 4; ++jt)
        atomicAdd(Oacc + ((size_t)qg * kH + h) * kDh + jt * 16 + lrow, oacc[jt][r]);
    }
  }
}

// ---------------------------------------------------------------- normalize: ho attn columns = Oacc / Lacc
__global__ __launch_bounds__(256) void norm_kernel(
    const float* __restrict__ Oacc, const float* __restrict__ Lacc,
    _Float16* __restrict__ ho) {
  const int idx = blockIdx.x * 256 + threadIdx.x;
  const int q = idx >> 10, rem = idx & 1023;
  const float l = Lacc[(q << 4) + (rem >> 6)];
  ho[(size_t)q * kKOut + kF + rem] = (_Float16)(Oacc[idx] / l);
}

// ---------------------------------------------------------------- launch
extern "C" void kernel_launch(void* const* d_in, const int* in_sizes, int n_in,
                              void* d_out, int out_size, void* d_ws, size_t ws_size,
                              hipStream_t stream) {
  const float* x        = (const float*)d_in[0];
  const float* ln_scale = (const float*)d_in[2];
  const float* ln_bias  = (const float*)d_in[3];
  const float* w_in     = (const float*)d_in[4];
  const float* b_in     = (const float*)d_in[5];
  const float* wq       = (const float*)d_in[6];
  const float* bq       = (const float*)d_in[7];
  const float* wk       = (const float*)d_in[8];
  const float* bk       = (const float*)d_in[9];
  const float* wv       = (const float*)d_in[10];
  const float* bv       = (const float*)d_in[11];
  const float* qn_scale = (const float*)d_in[12];
  const float* kn_scale = (const float*)d_in[13];
  const float* w_mo     = (const float*)d_in[14];
  const float* b_mo     = (const float*)d_in[15];
  const float* w_ao     = (const float*)d_in[16];
  const float* b_ao     = (const float*)d_in[17];
  float* out = (float*)d_out;

  char* ws = (char*)d_ws;
  size_t off = 0;
  auto alloc = [&](size_t bytes) { char* p = ws + off; off += bytes; return p; };
  // alias zone: xn+Wqkv dead after gemm_qkvin; Oacc/Lacc overlay
  char* zone = (char*)alloc((size_t)kS * kD * 2 + (size_t)kNQKV * kD * 2);
  _Float16* xn   = (_Float16*)zone;
  _Float16* Wqkv = (_Float16*)(zone + (size_t)kS * kD * 2);
  float* Oacc = (float*)zone;
  float* Lacc = (float*)(zone + (size_t)kS * kD * 4);
  _Float16* Wout = (_Float16*)alloc((size_t)kD * kKOut * 2);
  _Float16* ho   = (_Float16*)alloc((size_t)kS * kKOut * 2);
  _Float16* q_h  = (_Float16*)alloc((size_t)kS * kD * 2);
  _Float16* k_h  = (_Float16*)alloc((size_t)kS * kD * 2);
  _Float16* v_h  = (_Float16*)alloc((size_t)kS * kD * 2);
  _Float16* v_t  = (_Float16*)alloc((size_t)kS * kD * 2);

  prep0_kernel<<<12288 + 4096, 256, 0, stream>>>(
      w_in, wq, wk, wv, w_mo, w_ao, Wqkv, Wout, x, ln_scale, ln_bias, xn);

  gemm_qkvin<<<dim3(kS / 128, kNQKV / 128), 256, 0, stream>>>(
      xn, Wqkv, b_in, bq, bk, bv, qn_scale, kn_scale, ho, q_h, k_h, v_h);

  htrans_kernel<<<dim3(kD / 32, kS / 32), 256, 0, stream>>>(v_h, v_t, kS, kD);

  prep_kernel<<<(kS * kD + kS * kH + 255) / 256, 256, 0, stream>>>(
      x, b_mo, b_ao, out, Oacc, Lacc);

  fattn_kernel<<<dim3(32, kH, 2), 256, 0, stream>>>(q_h, k_h, v_t, Oacc, Lacc);

  norm_kernel<<<kS * kD / 256, 256, 0, stream>>>(Oacc, Lacc, ho);

  gemm_out<<<dim3(kS / 128, kD / 128, 2), 256, 0, stream>>>(ho, Wout, out);
}